// Round 1
// baseline (437.154 us; speedup 1.0000x reference)
//
#include <hip/hip_runtime.h>
#include <hip/hip_bf16.h>

#define B_ 16
#define S_ 8192
#define H_ 256
#define K_ 512           // 2H
#define MT_ 64           // rows per block tile
#define NBLK (S_/MT_)    // 128 s-tiles per batch

typedef __attribute__((ext_vector_type(8))) short bf16x8;
typedef __attribute__((ext_vector_type(4))) float f32x4;

static __device__ __forceinline__ unsigned short f2bf(float x) {
    __hip_bfloat16 h = __float2bfloat16(x);
    unsigned short r;
    __builtin_memcpy(&r, &h, 2);
    return r;
}

// ---------------------------------------------------------------------------
// Prep 1: repack W2[k][n] = attn_w[n][256+k] (bf16) into MFMA B-fragment order:
// wfrag[((nt*16+ks)*64 + lane)] holds 8 bf16: B[k = ks*32+(lane>>4)*8+j][n = nt*16+(lane&15)]
// ---------------------------------------------------------------------------
__global__ __launch_bounds__(256) void wprep_kernel(const float* __restrict__ w,
                                                    bf16x8* __restrict__ wfrag) {
    int slot = blockIdx.x * 256 + threadIdx.x;     // 0..16383
    int lane = slot & 63;
    int ks   = (slot >> 6) & 15;
    int nt   = slot >> 10;
    int n  = (nt << 4) + (lane & 15);
    int k0 = (ks << 5) + ((lane >> 4) << 3);
    const float* src = w + n * 768 + 256 + k0;     // attn_w[n][256+k0 ..]
    unsigned short u[8];
#pragma unroll
    for (int j = 0; j < 8; ++j) u[j] = f2bf(src[j]);
    uint4 p;
    p.x = (unsigned)u[0] | ((unsigned)u[1] << 16);
    p.y = (unsigned)u[2] | ((unsigned)u[3] << 16);
    p.z = (unsigned)u[4] | ((unsigned)u[5] << 16);
    p.w = (unsigned)u[6] | ((unsigned)u[7] << 16);
    ((uint4*)wfrag)[slot] = p;
}

// ---------------------------------------------------------------------------
// Prep 2: q[b][h] = attn_b[h] + sum_k attn_w[h][k] * hidden[b][k]   (fp32 exact)
// ---------------------------------------------------------------------------
__global__ __launch_bounds__(256) void qprep_kernel(const float* __restrict__ w,
                                                    const float* __restrict__ bias,
                                                    const float* __restrict__ hid,
                                                    float* __restrict__ q) {
    int b = blockIdx.x, h = threadIdx.x;
    const float* wr = w + h * 768;
    const float* hb = hid + b * H_;
    float acc = bias[h];
    for (int k = 0; k < H_; ++k) acc += wr[k] * hb[k];
    q[b * H_ + h] = acc;
}

// ---------------------------------------------------------------------------
// Main: per block, one (b, 64-row) tile. Stage enc tile bf16 into swizzled LDS,
// 4 waves x 4 n-tiles each, MFMA over K=512, fused tanh + v-dot + reduction.
// ---------------------------------------------------------------------------
__global__ __launch_bounds__(256) void energy_kernel(const float* __restrict__ enc,
                                                     const bf16x8* __restrict__ wfrag,
                                                     const float* __restrict__ qv,
                                                     const float* __restrict__ vv,
                                                     float* __restrict__ ener) {
    __shared__ char  At[MT_ * K_ * 2];      // 64 KB bf16, xor-swizzled rows
    __shared__ float epart[4][MT_];

    const int bid  = blockIdx.x;
    const int b    = bid >> 7;              // / NBLK
    const int s0   = (bid & 127) * MT_;
    const int tid  = threadIdx.x;
    const int lane = tid & 63;
    const int wv   = tid >> 6;
    const int lr   = lane & 15;
    const int lg   = lane >> 4;

    // ---- stage: 64 rows x 512 fp32 -> bf16 LDS ----
    const float* gbase = enc + ((size_t)(b * S_ + s0)) * K_;
#pragma unroll
    for (int j = 0; j < 16; ++j) {
        int chunk = j * 256 + tid;          // 0..4095, 8 bf16 per chunk
        int row = chunk >> 6;
        int k0  = (chunk & 63) << 3;
        const float4* gp = (const float4*)(gbase + row * K_ + k0);
        float4 f0 = gp[0], f1 = gp[1];
        uint4 p;
        p.x = (unsigned)f2bf(f0.x) | ((unsigned)f2bf(f0.y) << 16);
        p.y = (unsigned)f2bf(f0.z) | ((unsigned)f2bf(f0.w) << 16);
        p.z = (unsigned)f2bf(f1.x) | ((unsigned)f2bf(f1.y) << 16);
        p.w = (unsigned)f2bf(f1.z) | ((unsigned)f2bf(f1.w) << 16);
        int lin = chunk << 4;               // row*1024 + k0*2
        int sw  = lin ^ ((row & 7) << 4);
        *(uint4*)(At + sw) = p;
    }

    // per-lane q and v for my wave's 4 n-tiles
    float qreg[4], vreg[4];
#pragma unroll
    for (int n = 0; n < 4; ++n) {
        int col = (wv * 4 + n) * 16 + lr;
        qreg[n] = qv[b * H_ + col];
        vreg[n] = vv[col];
    }

    __syncthreads();

    f32x4 acc[4][4];                        // [m-tile][n-tile]
#pragma unroll
    for (int mt = 0; mt < 4; ++mt)
#pragma unroll
        for (int n = 0; n < 4; ++n)
            acc[mt][n] = (f32x4){0.f, 0.f, 0.f, 0.f};

#pragma unroll 4
    for (int ks = 0; ks < 16; ++ks) {
        bf16x8 a[4];
#pragma unroll
        for (int mt = 0; mt < 4; ++mt) {
            int row = mt * 16 + lr;
            int lin = row * 1024 + ks * 64 + lg * 16;
            int sw  = lin ^ ((row & 7) << 4);
            a[mt] = *(const bf16x8*)(At + sw);
        }
#pragma unroll
        for (int n = 0; n < 4; ++n) {
            bf16x8 bfr = wfrag[(((wv * 4 + n) * 16 + ks) << 6) + lane];
#pragma unroll
            for (int mt = 0; mt < 4; ++mt)
                acc[mt][n] = __builtin_amdgcn_mfma_f32_16x16x32_bf16(a[mt], bfr, acc[mt][n], 0, 0, 0);
        }
    }

    // ---- epilogue: e[row] += v[n] * tanh(q[n] + acc) , reduce 16 cols/lanegroup ----
#pragma unroll
    for (int mt = 0; mt < 4; ++mt) {
#pragma unroll
        for (int j = 0; j < 4; ++j) {
            float s = 0.f;
#pragma unroll
            for (int n = 0; n < 4; ++n)
                s += vreg[n] * tanhf(qreg[n] + acc[mt][n][j]);
            s += __shfl_xor(s, 1);
            s += __shfl_xor(s, 2);
            s += __shfl_xor(s, 4);
            s += __shfl_xor(s, 8);
            if (lr == 0) epart[wv][mt * 16 + lg * 4 + j] = s;
        }
    }
    __syncthreads();
    if (tid < MT_) {
        float s = epart[0][tid] + epart[1][tid] + epart[2][tid] + epart[3][tid];
        ener[b * S_ + s0 + tid] = s;
    }
}

// ---------------------------------------------------------------------------
// Softmax over S per batch
// ---------------------------------------------------------------------------
__global__ __launch_bounds__(1024) void softmax_kernel(const float* __restrict__ ener,
                                                       float* __restrict__ out) {
    __shared__ float redm[16], reds[16];
    int b = blockIdx.x, tid = threadIdx.x;
    int lane = tid & 63, wv = tid >> 6;
    const float* e = ener + b * S_;
    float v[8];
#pragma unroll
    for (int i = 0; i < 8; ++i) v[i] = e[i * 1024 + tid];
    float m = v[0];
#pragma unroll
    for (int i = 1; i < 8; ++i) m = fmaxf(m, v[i]);
#pragma unroll
    for (int msk = 1; msk < 64; msk <<= 1) m = fmaxf(m, __shfl_xor(m, msk));
    if (lane == 0) redm[wv] = m;
    __syncthreads();
    float M = redm[0];
#pragma unroll
    for (int i = 1; i < 16; ++i) M = fmaxf(M, redm[i]);
    float s = 0.f;
#pragma unroll
    for (int i = 0; i < 8; ++i) { v[i] = __expf(v[i] - M); s += v[i]; }
#pragma unroll
    for (int msk = 1; msk < 64; msk <<= 1) s += __shfl_xor(s, msk);
    if (lane == 0) reds[wv] = s;
    __syncthreads();
    float T = 0.f;
#pragma unroll
    for (int i = 0; i < 16; ++i) T += reds[i];
    float inv = 1.0f / T;
    float* ob = out + b * S_;
#pragma unroll
    for (int i = 0; i < 8; ++i) ob[i * 1024 + tid] = v[i] * inv;
}

extern "C" void kernel_launch(void* const* d_in, const int* in_sizes, int n_in,
                              void* d_out, int out_size, void* d_ws, size_t ws_size,
                              hipStream_t stream) {
    const float* hidden = (const float*)d_in[0];
    const float* enc    = (const float*)d_in[1];
    const float* attn_w = (const float*)d_in[2];
    const float* attn_b = (const float*)d_in[3];
    const float* v      = (const float*)d_in[4];
    float* out = (float*)d_out;

    char* ws = (char*)d_ws;
    bf16x8* wfrag = (bf16x8*)ws;                          // 256 KB
    float*  q     = (float*)(ws + 262144);                // 16 KB
    float*  ener  = (float*)(ws + 262144 + 16384);        // 512 KB

    wprep_kernel<<<64, 256, 0, stream>>>(attn_w, wfrag);
    qprep_kernel<<<B_, 256, 0, stream>>>(attn_w, attn_b, hidden, q);
    energy_kernel<<<B_ * NBLK, 256, 0, stream>>>(enc, wfrag, q, v, ener);
    softmax_kernel<<<B_, 1024, 0, stream>>>(ener, out);
}